// Round 6
// baseline (2561.492 us; speedup 1.0000x reference)
//
#include <hip/hip_runtime.h>
#include <hip/hip_bf16.h>

#define NU 50000
#define NI 30000
#define NN 80000     // NU + NI
#define KDIM 64
#define DD0 768
#define DD1 128
#define DD 896       // DD0 + DD1 = 14 chunks of 64

#define BROWS 128            // dst rows per bucket
#define NB (NN / BROWS)      // 625 buckets (80000 = 625*128 exactly)
#define CAPB 5120            // entries per bucket region (mean ~3200-4300, +13 sigma)
#define CHUNK_PAIRS 4096     // edge pairs per partition WG

// ---------------------------------------------------------------------------
// 1) F_proj = l2norm(concat(F0,F1) @ W + b).
// Writes raw row into acc (layer-0 accumulator) and dinv-scaled row into curS.
// ---------------------------------------------------------------------------
__global__ __launch_bounds__(256) void proj_kernel(
    const float* __restrict__ F0, const float* __restrict__ F1,
    const float* __restrict__ W, const float* __restrict__ b,
    const float* __restrict__ dinv,
    float* __restrict__ acc_out, float* __restrict__ curS)
{
    __shared__ float Ft[64][68];   // [kk][rowLoc], padded
    __shared__ float Wt[64][64];   // [kk][col]

    const int tid = threadIdx.x;
    const int ty  = tid >> 4;
    const int tx  = tid & 15;
    const int rowBase = blockIdx.x * 64;

    float acc[4][4] = {};

    for (int c = 0; c < 14; ++c) {
        #pragma unroll
        for (int rep = 0; rep < 4; ++rep) {
            const int idx  = rep * 256 + tid;
            const int rLoc = idx >> 4;
            const int kq   = idx & 15;
            const int r    = rowBase + rLoc;
            float4 v = make_float4(0.f, 0.f, 0.f, 0.f);
            if (r < NI) {
                if (c < 12)
                    v = *(const float4*)&F0[(size_t)r * DD0 + c * 64 + kq * 4];
                else
                    v = *(const float4*)&F1[(size_t)r * DD1 + (c - 12) * 64 + kq * 4];
            }
            Ft[kq * 4 + 0][rLoc] = v.x;
            Ft[kq * 4 + 1][rLoc] = v.y;
            Ft[kq * 4 + 2][rLoc] = v.z;
            Ft[kq * 4 + 3][rLoc] = v.w;
        }
        #pragma unroll
        for (int rep = 0; rep < 4; ++rep) {
            const int idx = rep * 256 + tid;
            const int kk  = idx >> 4;
            const int cq  = idx & 15;
            *(float4*)&Wt[kk][cq * 4] =
                *(const float4*)&W[(size_t)(c * 64 + kk) * KDIM + cq * 4];
        }
        __syncthreads();

        #pragma unroll 4
        for (int kk = 0; kk < 64; ++kk) {
            const float4 a = *(const float4*)&Ft[kk][ty * 4];
            const float4 w = *(const float4*)&Wt[kk][tx * 4];
            const float av[4] = {a.x, a.y, a.z, a.w};
            const float wv[4] = {w.x, w.y, w.z, w.w};
            #pragma unroll
            for (int i = 0; i < 4; ++i)
                #pragma unroll
                for (int j = 0; j < 4; ++j)
                    acc[i][j] += av[i] * wv[j];
        }
        __syncthreads();
    }

    const float4 bv = *(const float4*)&b[tx * 4];
    const float bias[4] = {bv.x, bv.y, bv.z, bv.w};
    #pragma unroll
    for (int i = 0; i < 4; ++i) {
        float y[4];
        float ss = 0.f;
        #pragma unroll
        for (int j = 0; j < 4; ++j) {
            y[j] = acc[i][j] + bias[j];
            ss += y[j] * y[j];
        }
        ss += __shfl_xor(ss, 1);
        ss += __shfl_xor(ss, 2);
        ss += __shfl_xor(ss, 4);
        ss += __shfl_xor(ss, 8);
        const float inv = 1.0f / fmaxf(sqrtf(ss), 1e-12f);
        const int r = rowBase + ty * 4 + i;
        if (r < NI) {
            const float dv = dinv[NU + r];
            float4 o, oS;
            o.x = y[0] * inv; o.y = y[1] * inv; o.z = y[2] * inv; o.w = y[3] * inv;
            oS.x = o.x * dv; oS.y = o.y * dv; oS.z = o.z * dv; oS.w = o.w * dv;
            *(float4*)&acc_out[(size_t)(NU + r) * KDIM + tx * 4] = o;
            *(float4*)&curS[(size_t)(NU + r) * KDIM + tx * 4]    = oS;
        }
    }
}

// user rows: acc = Gu, curS = Gu * dinv[row]
__global__ void userinit_kernel(const float* __restrict__ Gu,
                                const float* __restrict__ dinv,
                                float* __restrict__ acc,
                                float* __restrict__ curS)
{
    const int i = blockIdx.x * blockDim.x + threadIdx.x;  // float4 index
    if (i < NU * KDIM / 4) {
        const int row = i >> 4;
        const float dv = dinv[row];
        const float4 g = ((const float4*)Gu)[i];
        ((float4*)acc)[i] = g;
        float4 s;
        s.x = g.x * dv; s.y = g.y * dv; s.z = g.z * dv; s.w = g.w * dv;
        ((float4*)curS)[i] = s;
    }
}

// ---------------------------------------------------------------------------
// Partition: bucket the 2M directed entries by dst>>7. Per-WG LDS counting,
// one global cursor atomic per (WG,bucket), then clustered 4B entry writes.
// Entry = (dst&127)<<16 | src16  (src16 = user id, or item id - NU; the dst
// row determines which, since the graph is bipartite).
// ---------------------------------------------------------------------------
__global__ __launch_bounds__(256) void part_kernel(
    const int* __restrict__ src, const int* __restrict__ dst,
    int* __restrict__ bcur, unsigned int* __restrict__ ents, int E2)
{
    __shared__ int bcntL[NB];
    __shared__ int bposL[NB];
    const int tid = threadIdx.x;
    const int pairBase = blockIdx.x * CHUNK_PAIRS;

    for (int i = tid; i < NB; i += 256) bcntL[i] = 0;
    __syncthreads();

    // pass 1: count
    #pragma unroll
    for (int it = 0; it < CHUNK_PAIRS / 256; ++it) {
        const int p = pairBase + it * 256 + tid;
        if (p < E2) {
            const int u  = src[p];      // 0..NU-1
            const int iF = dst[p];      // NU..NN-1
            atomicAdd(&bcntL[iF >> 7], 1);
            atomicAdd(&bcntL[u  >> 7], 1);
        }
    }
    __syncthreads();

    // reserve global space per bucket
    for (int bkt = tid; bkt < NB; bkt += 256) {
        const int c = bcntL[bkt];
        bposL[bkt] = (c > 0) ? atomicAdd(&bcur[bkt], c) : 0;
        bcntL[bkt] = 0;                 // reuse as local cursor
    }
    __syncthreads();

    // pass 2: place
    #pragma unroll
    for (int it = 0; it < CHUNK_PAIRS / 256; ++it) {
        const int p = pairBase + it * 256 + tid;
        if (p < E2) {
            const int u  = src[p];
            const int iF = dst[p];
            // entry A: dst = item row, payload = user id
            {
                const int bkt = iF >> 7;
                const int k = bposL[bkt] + atomicAdd(&bcntL[bkt], 1);
                if (k < CAPB)
                    ents[(size_t)bkt * CAPB + k] =
                        ((unsigned int)(iF & 127) << 16) | (unsigned int)u;
            }
            // entry B: dst = user row, payload = item id - NU
            {
                const int bkt = u >> 7;
                const int k = bposL[bkt] + atomicAdd(&bcntL[bkt], 1);
                if (k < CAPB)
                    ents[(size_t)bkt * CAPB + k] =
                        ((unsigned int)(u & 127) << 16) | (unsigned int)(iF - NU);
            }
        }
    }
}

// per-bucket degree histogram -> cnt (dense writes)
__global__ __launch_bounds__(256) void deg_kernel(
    const unsigned int* __restrict__ ents, const int* __restrict__ bcur,
    int* __restrict__ cnt)
{
    __shared__ int dcnt[BROWS];
    const int bkt = blockIdx.x;
    const int tid = threadIdx.x;
    if (tid < BROWS) dcnt[tid] = 0;
    __syncthreads();
    int n = bcur[bkt]; n = (n < CAPB) ? n : CAPB;
    const unsigned int* ep = ents + (size_t)bkt * CAPB;
    for (int j = tid; j < n; j += 256)
        atomicAdd(&dcnt[ep[j] >> 16], 1);
    __syncthreads();
    if (tid < BROWS) cnt[bkt * BROWS + tid] = dcnt[tid];
}

__global__ void dinv_kernel(const int* __restrict__ cnt,
                            float* __restrict__ dinv, int n)
{
    const int i = blockIdx.x * blockDim.x + threadIdx.x;
    if (i < n) {
        const int d = cnt[i];
        dinv[i] = (d > 0) ? rsqrtf((float)d) : 0.0f;
    }
}

// ---------------------------------------------------------------------------
// 3) bucketed pull: WG per bucket, 32KB LDS accumulator [128][64].
//    a[dl] = sum over entries curS[src];  then per row:
//    acc[row] += dinv*a;  nxtS[row] = dinv^2*a (skipped last layer)
// ---------------------------------------------------------------------------
template <bool WRITE_NEXT>
__global__ __launch_bounds__(512) void pullB_kernel(
    const float* __restrict__ curS, float* __restrict__ nxtS,
    float* __restrict__ accG,
    const unsigned int* __restrict__ ents, const int* __restrict__ bcur,
    const float* __restrict__ dinv)
{
    __shared__ float accL[BROWS][KDIM];   // 32 KB
    const int bkt  = blockIdx.x;
    const int tid  = threadIdx.x;
    const int wv   = tid >> 6;            // 0..7
    const int lane = tid & 63;

    #pragma unroll
    for (int i = tid; i < BROWS * KDIM; i += 512)
        ((float*)accL)[i] = 0.0f;
    __syncthreads();

    int n = bcur[bkt]; n = (n < CAPB) ? n : CAPB;
    const unsigned int* ep = ents + (size_t)bkt * CAPB;
    const int rowB = bkt * BROWS;

    for (int jb = wv * 64; jb < n; jb += 512) {
        const int j = jb + lane;
        const unsigned int e = (j < n) ? ep[j] : 0u;
        const int m = (n - jb < 64) ? (n - jb) : 64;
        #pragma unroll 4
        for (int q = 0; q < m; ++q) {
            const unsigned int eq = (unsigned int)__shfl((int)e, q);
            const int dl  = (int)(eq >> 16);
            const int s16 = (int)(eq & 0xFFFFu);
            const int row = rowB + dl;
            const int srcF = (row < NU) ? (s16 + NU) : s16;  // bipartite
            const float v = curS[(size_t)srcF * KDIM + lane];
            unsafeAtomicAdd(&accL[dl][lane], v);
        }
    }
    __syncthreads();

    for (int dl = wv; dl < BROWS; dl += 8) {
        const int row = rowB + dl;
        const float a  = accL[dl][lane];
        const float dv = dinv[row];
        const float val = dv * a;
        accG[(size_t)row * KDIM + lane] += val;
        if (WRITE_NEXT)
            nxtS[(size_t)row * KDIM + lane] = dv * val;
    }
}

// ---------------------------------------------------------------------------
// 4) xui[b] = (1/16) * dot(acc[user[b]], acc[NU + item[b]])
// ---------------------------------------------------------------------------
__global__ __launch_bounds__(256) void out_kernel(
    const float* __restrict__ acc, const int* __restrict__ uidx,
    const int* __restrict__ iidx, float* __restrict__ out, int B)
{
    const int wid  = (blockIdx.x * blockDim.x + threadIdx.x) >> 6;
    const int lane = threadIdx.x & 63;
    if (wid >= B) return;
    const int u  = uidx[wid];
    const int it = iidx[wid];
    float p = acc[(size_t)u * KDIM + lane] * acc[(size_t)(NU + it) * KDIM + lane];
    #pragma unroll
    for (int m = 32; m >= 1; m >>= 1) p += __shfl_xor(p, m);
    if (lane == 0) out[wid] = p * (1.0f / 16.0f);
}

extern "C" void kernel_launch(void* const* d_in, const int* in_sizes, int n_in,
                              void* d_out, int out_size, void* d_ws, size_t ws_size,
                              hipStream_t stream)
{
    const float* Gu = (const float*)d_in[0];
    const float* F0 = (const float*)d_in[1];
    const float* F1 = (const float*)d_in[2];
    const float* W  = (const float*)d_in[3];
    const float* pb = (const float*)d_in[4];
    const int* edge = (const int*)d_in[5];
    const int* uidx = (const int*)d_in[6];
    const int* iidx = (const int*)d_in[7];
    const int E  = in_sizes[5] / 2;      // 2,000,000 directed edges
    const int E2 = E / 2;                // 1,000,000 mirrored pairs
    const int B = in_sizes[6];           // 4096
    const int* srcp = edge;              // first E2: user ids
    const int* dstp = edge + E;          // first E2: item ids (+NU)

    const size_t XE = (size_t)NN * KDIM;
    float* acc   = (float*)d_ws;                   // XE
    float* curA  = acc + XE;                       // XE
    float* curB  = curA + XE;                      // XE
    float* dinv  = curB + XE;                      // NN
    int*   cnt   = (int*)(dinv + NN);              // NN
    int*   bcur  = cnt + NN;                       // NB
    unsigned int* ents = (unsigned int*)(bcur + NB);  // NB*CAPB (~12.8 MB)
    // total ~75 MB

    // partition edges into per-bucket entry lists; degrees; dinv
    hipMemsetAsync(bcur, 0, NB * sizeof(int), stream);
    part_kernel<<<(E2 + CHUNK_PAIRS - 1) / CHUNK_PAIRS, 256, 0, stream>>>(
        srcp, dstp, bcur, ents, E2);
    deg_kernel<<<NB, 256, 0, stream>>>(ents, bcur, cnt);
    dinv_kernel<<<(NN + 255) / 256, 256, 0, stream>>>(cnt, dinv, NN);

    // x0: acc = [Gu; Fproj], curA = dinv .* x0
    userinit_kernel<<<(NU * KDIM / 4 + 255) / 256, 256, 0, stream>>>(
        Gu, dinv, acc, curA);
    proj_kernel<<<(NI + 63) / 64, 256, 0, stream>>>(F0, F1, W, pb, dinv,
                                                    acc, curA);

    // 3 propagation layers (bucketed pull)
    pullB_kernel<true ><<<NB, 512, 0, stream>>>(curA, curB, acc, ents, bcur, dinv);
    pullB_kernel<true ><<<NB, 512, 0, stream>>>(curB, curA, acc, ents, bcur, dinv);
    pullB_kernel<false><<<NB, 512, 0, stream>>>(curA, nullptr, acc, ents, bcur, dinv);

    out_kernel<<<(int)(((size_t)B * 64 + 255) / 256), 256, 0, stream>>>(
        acc, uidx, iidx, (float*)d_out, B);
}

// Round 7
// 336.551 us; speedup vs baseline: 7.6110x; 7.6110x over previous
//
#include <hip/hip_runtime.h>
#include <hip/hip_bf16.h>

#define NU 50000
#define NI 30000
#define NN 80000     // NU + NI
#define KDIM 64
#define DD0 768
#define DD1 128
#define DD 896       // DD0 + DD1 = 14 chunks of 64

#define BROWS 128            // dst rows per bucket
#define NB (NN / BROWS)      // 625 buckets (80000 = 625*128 exactly)
#define CAPB 5120            // entries per bucket region (mean 2560-4267, +13 sigma)
#define CAP 96               // uniform ELL capacity per row (u16 slots)
#define REGION_BYTES 24576   // per-bucket region: max(CAPB*4, 128*CAP*2) = 24 KB
#define ENTS_STRIDE (REGION_BYTES / 4)   // 6144 u32 per region
#define CHUNK_PAIRS 4096     // edge pairs per partition WG

// ---------------------------------------------------------------------------
// 1) F_proj = l2norm(concat(F0,F1) @ W + b).
// Writes raw row into acc (layer-0 accumulator) and dinv-scaled row into curS.
// ---------------------------------------------------------------------------
__global__ __launch_bounds__(256) void proj_kernel(
    const float* __restrict__ F0, const float* __restrict__ F1,
    const float* __restrict__ W, const float* __restrict__ b,
    const float* __restrict__ dinv,
    float* __restrict__ acc_out, float* __restrict__ curS)
{
    __shared__ float Ft[64][68];   // [kk][rowLoc], padded
    __shared__ float Wt[64][64];   // [kk][col]

    const int tid = threadIdx.x;
    const int ty  = tid >> 4;
    const int tx  = tid & 15;
    const int rowBase = blockIdx.x * 64;

    float acc[4][4] = {};

    for (int c = 0; c < 14; ++c) {
        #pragma unroll
        for (int rep = 0; rep < 4; ++rep) {
            const int idx  = rep * 256 + tid;
            const int rLoc = idx >> 4;
            const int kq   = idx & 15;
            const int r    = rowBase + rLoc;
            float4 v = make_float4(0.f, 0.f, 0.f, 0.f);
            if (r < NI) {
                if (c < 12)
                    v = *(const float4*)&F0[(size_t)r * DD0 + c * 64 + kq * 4];
                else
                    v = *(const float4*)&F1[(size_t)r * DD1 + (c - 12) * 64 + kq * 4];
            }
            Ft[kq * 4 + 0][rLoc] = v.x;
            Ft[kq * 4 + 1][rLoc] = v.y;
            Ft[kq * 4 + 2][rLoc] = v.z;
            Ft[kq * 4 + 3][rLoc] = v.w;
        }
        #pragma unroll
        for (int rep = 0; rep < 4; ++rep) {
            const int idx = rep * 256 + tid;
            const int kk  = idx >> 4;
            const int cq  = idx & 15;
            *(float4*)&Wt[kk][cq * 4] =
                *(const float4*)&W[(size_t)(c * 64 + kk) * KDIM + cq * 4];
        }
        __syncthreads();

        #pragma unroll 4
        for (int kk = 0; kk < 64; ++kk) {
            const float4 a = *(const float4*)&Ft[kk][ty * 4];
            const float4 w = *(const float4*)&Wt[kk][tx * 4];
            const float av[4] = {a.x, a.y, a.z, a.w};
            const float wv[4] = {w.x, w.y, w.z, w.w};
            #pragma unroll
            for (int i = 0; i < 4; ++i)
                #pragma unroll
                for (int j = 0; j < 4; ++j)
                    acc[i][j] += av[i] * wv[j];
        }
        __syncthreads();
    }

    const float4 bv = *(const float4*)&b[tx * 4];
    const float bias[4] = {bv.x, bv.y, bv.z, bv.w};
    #pragma unroll
    for (int i = 0; i < 4; ++i) {
        float y[4];
        float ss = 0.f;
        #pragma unroll
        for (int j = 0; j < 4; ++j) {
            y[j] = acc[i][j] + bias[j];
            ss += y[j] * y[j];
        }
        ss += __shfl_xor(ss, 1);
        ss += __shfl_xor(ss, 2);
        ss += __shfl_xor(ss, 4);
        ss += __shfl_xor(ss, 8);
        const float inv = 1.0f / fmaxf(sqrtf(ss), 1e-12f);
        const int r = rowBase + ty * 4 + i;
        if (r < NI) {
            const float dv = dinv[NU + r];
            float4 o, oS;
            o.x = y[0] * inv; o.y = y[1] * inv; o.z = y[2] * inv; o.w = y[3] * inv;
            oS.x = o.x * dv; oS.y = o.y * dv; oS.z = o.z * dv; oS.w = o.w * dv;
            *(float4*)&acc_out[(size_t)(NU + r) * KDIM + tx * 4] = o;
            *(float4*)&curS[(size_t)(NU + r) * KDIM + tx * 4]    = oS;
        }
    }
}

// user rows: acc = Gu, curS = Gu * dinv[row]
__global__ void userinit_kernel(const float* __restrict__ Gu,
                                const float* __restrict__ dinv,
                                float* __restrict__ acc,
                                float* __restrict__ curS)
{
    const int i = blockIdx.x * blockDim.x + threadIdx.x;  // float4 index
    if (i < NU * KDIM / 4) {
        const int row = i >> 4;
        const float dv = dinv[row];
        const float4 g = ((const float4*)Gu)[i];
        ((float4*)acc)[i] = g;
        float4 s;
        s.x = g.x * dv; s.y = g.y * dv; s.z = g.z * dv; s.w = g.w * dv;
        ((float4*)curS)[i] = s;
    }
}

// ---------------------------------------------------------------------------
// Partition: bucket the 2M directed entries by dst>>7. Per-WG LDS counting,
// one global cursor atomic per (WG,bucket), then clustered 4B entry writes.
// Entry = (dst&127)<<16 | payload16. Bipartite payload: for an item-row dst
// the payload is the user id; for a user-row dst it is item id - NU.
// Writes for a bucket region come from one WG -> one L2 -> merged lines.
// ---------------------------------------------------------------------------
__global__ __launch_bounds__(256) void part_kernel(
    const int* __restrict__ src, const int* __restrict__ dst,
    int* __restrict__ bcur, unsigned int* __restrict__ ents, int E2)
{
    __shared__ int bcntL[NB];
    __shared__ int bposL[NB];
    const int tid = threadIdx.x;
    const int pairBase = blockIdx.x * CHUNK_PAIRS;

    for (int i = tid; i < NB; i += 256) bcntL[i] = 0;
    __syncthreads();

    // pass 1: count
    #pragma unroll
    for (int it = 0; it < CHUNK_PAIRS / 256; ++it) {
        const int p = pairBase + it * 256 + tid;
        if (p < E2) {
            const int u  = src[p];      // 0..NU-1
            const int iF = dst[p];      // NU..NN-1
            atomicAdd(&bcntL[iF >> 7], 1);
            atomicAdd(&bcntL[u  >> 7], 1);
        }
    }
    __syncthreads();

    // reserve global space per bucket
    for (int bkt = tid; bkt < NB; bkt += 256) {
        const int c = bcntL[bkt];
        bposL[bkt] = (c > 0) ? atomicAdd(&bcur[bkt], c) : 0;
        bcntL[bkt] = 0;                 // reuse as local cursor
    }
    __syncthreads();

    // pass 2: place
    #pragma unroll
    for (int it = 0; it < CHUNK_PAIRS / 256; ++it) {
        const int p = pairBase + it * 256 + tid;
        if (p < E2) {
            const int u  = src[p];
            const int iF = dst[p];
            {   // entry A: dst = item row, payload = user id
                const int bkt = iF >> 7;
                const int k = bposL[bkt] + atomicAdd(&bcntL[bkt], 1);
                if (k < CAPB)
                    ents[(size_t)bkt * ENTS_STRIDE + k] =
                        ((unsigned int)(iF & 127) << 16) | (unsigned int)u;
            }
            {   // entry B: dst = user row, payload = item id - NU
                const int bkt = u >> 7;
                const int k = bposL[bkt] + atomicAdd(&bcntL[bkt], 1);
                if (k < CAPB)
                    ents[(size_t)bkt * ENTS_STRIDE + k] =
                        ((unsigned int)(u & 127) << 16) | (unsigned int)(iF - NU);
            }
        }
    }
}

// ---------------------------------------------------------------------------
// toELL: one WG per bucket. Stage the bucket's entries in LDS (the ELL output
// region ALIASES the entry region, so staging must complete first), then
// place each entry into the row-major u16 ELL [row][CAP] via LDS cursors.
// Also emits cnt (degree) and dinv for the bucket's 128 rows.
// ---------------------------------------------------------------------------
__global__ __launch_bounds__(256) void toELL_kernel(
    const int* __restrict__ bcur, unsigned int* __restrict__ ents,
    unsigned short* __restrict__ col,
    int* __restrict__ cnt, float* __restrict__ dinv)
{
    __shared__ unsigned int eL[CAPB];   // 20 KB
    __shared__ int curL[BROWS];
    const int bkt = blockIdx.x;
    const int tid = threadIdx.x;

    int n = bcur[bkt]; n = (n < CAPB) ? n : CAPB;
    const unsigned int* ep = ents + (size_t)bkt * ENTS_STRIDE;

    for (int j = tid; j < n; j += 256) eL[j] = ep[j];
    if (tid < BROWS) curL[tid] = 0;
    __syncthreads();

    const size_t rowB = (size_t)bkt * BROWS;
    for (int j = tid; j < n; j += 256) {
        const unsigned int e = eL[j];
        const int dl = (int)(e >> 16);
        const int slot = atomicAdd(&curL[dl], 1);
        if (slot < CAP)
            col[(rowB + dl) * CAP + slot] = (unsigned short)(e & 0xFFFFu);
    }
    __syncthreads();

    if (tid < BROWS) {
        int c = curL[tid];
        c = (c < CAP) ? c : CAP;
        const size_t row = rowB + tid;
        cnt[row]  = c;
        dinv[row] = (c > 0) ? rsqrtf((float)c) : 0.0f;
    }
}

// ---------------------------------------------------------------------------
// 3) pull over pre-scaled state (R5-proven wave-per-row, 8-deep gathers):
//    a = sum_j curS[col_j];  acc[row] += dinv*a;  nxtS[row] = dinv^2*a
// ---------------------------------------------------------------------------
template <bool WRITE_NEXT>
__global__ __launch_bounds__(256) void pull_kernel(
    const float* __restrict__ curS, float* __restrict__ nxtS,
    float* __restrict__ acc,
    const int* __restrict__ cnt,
    const unsigned short* __restrict__ col,
    const float* __restrict__ dinv)
{
    const int row  = (blockIdx.x * blockDim.x + threadIdx.x) >> 6;
    const int lane = threadIdx.x & 63;
    if (row >= NN) return;

    const unsigned short* cp = col + (size_t)row * CAP;
    const int addB = (row < NU) ? NU : 0;   // bipartite payload offset
    const int n = cnt[row];

    float a0 = 0.0f, a1 = 0.0f;
    int j = 0;
    for (; j + 8 <= n; j += 8) {
        int s[8];
        #pragma unroll
        for (int q = 0; q < 8; ++q) s[q] = (int)cp[j + q] + addB;
        float v[8];
        #pragma unroll
        for (int q = 0; q < 8; ++q) v[q] = curS[(size_t)s[q] * KDIM + lane];
        a0 += v[0] + v[2] + v[4] + v[6];
        a1 += v[1] + v[3] + v[5] + v[7];
    }
    for (; j < n; ++j)
        a0 += curS[(size_t)((int)cp[j] + addB) * KDIM + lane];

    const float a  = a0 + a1;
    const float dv = dinv[row];
    const float val = dv * a;
    acc[(size_t)row * KDIM + lane] += val;
    if (WRITE_NEXT)
        nxtS[(size_t)row * KDIM + lane] = dv * val;
}

// ---------------------------------------------------------------------------
// 4) xui[b] = (1/16) * dot(acc[user[b]], acc[NU + item[b]])
// ---------------------------------------------------------------------------
__global__ __launch_bounds__(256) void out_kernel(
    const float* __restrict__ acc, const int* __restrict__ uidx,
    const int* __restrict__ iidx, float* __restrict__ out, int B)
{
    const int wid  = (blockIdx.x * blockDim.x + threadIdx.x) >> 6;
    const int lane = threadIdx.x & 63;
    if (wid >= B) return;
    const int u  = uidx[wid];
    const int it = iidx[wid];
    float p = acc[(size_t)u * KDIM + lane] * acc[(size_t)(NU + it) * KDIM + lane];
    #pragma unroll
    for (int m = 32; m >= 1; m >>= 1) p += __shfl_xor(p, m);
    if (lane == 0) out[wid] = p * (1.0f / 16.0f);
}

extern "C" void kernel_launch(void* const* d_in, const int* in_sizes, int n_in,
                              void* d_out, int out_size, void* d_ws, size_t ws_size,
                              hipStream_t stream)
{
    const float* Gu = (const float*)d_in[0];
    const float* F0 = (const float*)d_in[1];
    const float* F1 = (const float*)d_in[2];
    const float* W  = (const float*)d_in[3];
    const float* pb = (const float*)d_in[4];
    const int* edge = (const int*)d_in[5];
    const int* uidx = (const int*)d_in[6];
    const int* iidx = (const int*)d_in[7];
    const int E  = in_sizes[5] / 2;      // 2,000,000 directed edges
    const int E2 = E / 2;                // 1,000,000 mirrored pairs
    const int B = in_sizes[6];           // 4096
    const int* srcp = edge;              // first E2: user ids
    const int* dstp = edge + E;          // first E2: item ids (+NU)

    const size_t XE = (size_t)NN * KDIM;
    float* acc   = (float*)d_ws;                   // XE
    float* curA  = acc + XE;                       // XE
    float* curB  = curA + XE;                      // XE
    float* dinv  = curB + XE;                      // NN
    int*   cnt   = (int*)(dinv + NN);              // NN
    int*   bcur  = cnt + NN;                       // NB
    // col/ents share one region array: 625 regions x 24 KB = 15.36 MB
    unsigned short* col  = (unsigned short*)(bcur + NB);
    unsigned int*   ents = (unsigned int*)col;
    // total ~77.4 MB (<= 78.7 MB proven available in R3)

    // build: partition -> bucket-local ELL (also emits cnt, dinv)
    hipMemsetAsync(bcur, 0, NB * sizeof(int), stream);
    part_kernel<<<(E2 + CHUNK_PAIRS - 1) / CHUNK_PAIRS, 256, 0, stream>>>(
        srcp, dstp, bcur, ents, E2);
    toELL_kernel<<<NB, 256, 0, stream>>>(bcur, ents, col, cnt, dinv);

    // x0: acc = [Gu; Fproj], curA = dinv .* x0
    userinit_kernel<<<(NU * KDIM / 4 + 255) / 256, 256, 0, stream>>>(
        Gu, dinv, acc, curA);
    proj_kernel<<<(NI + 63) / 64, 256, 0, stream>>>(F0, F1, W, pb, dinv,
                                                    acc, curA);

    // 3 propagation layers (R5-proven pull)
    const int pullGrid = (int)((XE + 255) / 256);
    pull_kernel<true ><<<pullGrid, 256, 0, stream>>>(curA, curB, acc, cnt, col, dinv);
    pull_kernel<true ><<<pullGrid, 256, 0, stream>>>(curB, curA, acc, cnt, col, dinv);
    pull_kernel<false><<<pullGrid, 256, 0, stream>>>(curA, nullptr, acc, cnt, col, dinv);

    out_kernel<<<(int)(((size_t)B * 64 + 255) / 256), 256, 0, stream>>>(
        acc, uidx, iidx, (float*)d_out, B);
}

// Round 9
// 285.458 us; speedup vs baseline: 8.9733x; 1.1790x over previous
//
#include <hip/hip_runtime.h>
#include <hip/hip_bf16.h>

#define NU 50000
#define NI 30000
#define NN 80000     // NU + NI
#define KDIM 64
#define DD0 768
#define DD1 128
#define DD 896       // DD0 + DD1 = 14 chunks of 64

#define BROWS 128            // dst rows per bucket
#define NB (NN / BROWS)      // 625 buckets
#define CAPB 5120            // entries per bucket region
#define CAP 96               // uniform ELL capacity per row (u16 slots)
#define REGION_BYTES 24576   // per-bucket region
#define ENTS_STRIDE (REGION_BYTES / 4)
#define CHUNK_PAIRS 4096

typedef __attribute__((ext_vector_type(8))) short short8v;
typedef __attribute__((ext_vector_type(4))) short short4v;
typedef __attribute__((ext_vector_type(4))) float float4v;
typedef unsigned short ushort_t;

struct bf16pair { short hi, lo; };

__device__ inline bf16pair f32_split_bf16(float v) {
    __hip_bfloat16 h = __float2bfloat16(v);
    float hf = __bfloat162float(h);
    __hip_bfloat16 l = __float2bfloat16(v - hf);
    bf16pair p;
    p.hi = *reinterpret_cast<short*>(&h);
    p.lo = *reinterpret_cast<short*>(&l);
    return p;
}

__device__ inline float bf16bits_to_f32(ushort_t u) {
    return __uint_as_float(((unsigned int)u) << 16);
}

__device__ inline ushort_t f32_to_bf16_rne(float f) {
    unsigned int u = __float_as_uint(f);
    unsigned int r = (u + 0x7FFFu + ((u >> 16) & 1u)) >> 16;
    return (ushort_t)r;
}

// ---------------------------------------------------------------------------
// W -> transposed bf16 hi/lo:  WTh/WTl[col][k]  (col 0..63, k 0..895)
// ---------------------------------------------------------------------------
__global__ void wtcvt_kernel(const float* __restrict__ W,
                             short* __restrict__ WTh, short* __restrict__ WTl)
{
    const int i = blockIdx.x * 256 + threadIdx.x;   // over DD*KDIM
    if (i < DD * KDIM) {
        const int k = i >> 6, col = i & 63;
        const bf16pair p = f32_split_bf16(W[i]);
        WTh[col * DD + k] = p.hi;
        WTl[col * DD + k] = p.lo;
    }
}

// ---------------------------------------------------------------------------
// 1) proj via bf16x2-split MFMA: F_proj = l2norm(concat(F0,F1) @ W + b).
// Block 256 (4 waves), tile 64 rows x 64 cols, K chunks of 64.
// Wave w computes rows w*16..+15 (4 n-tiles of 16x16 via mfma 16x16x32).
// LDS rows padded to 72 shorts (144 B) -> bank-balanced frag reads.
// Writes raw f32 row into acc, bf16 dinv-scaled row into curS.
// ---------------------------------------------------------------------------
__global__ __launch_bounds__(256) void proj_kernel(
    const float* __restrict__ F0, const float* __restrict__ F1,
    const short* __restrict__ WTh, const short* __restrict__ WTl,
    const float* __restrict__ b, const float* __restrict__ dinv,
    float* __restrict__ acc_out, ushort_t* __restrict__ curS)
{
    __shared__ short Ah[64][72];
    __shared__ short Al[64][72];
    __shared__ short Bh[64][72];
    __shared__ short Bl[64][72];

    const int tid  = threadIdx.x;
    const int wv   = tid >> 6;      // wave 0..3
    const int lane = tid & 63;
    const int lr   = lane & 15;     // frag row/col
    const int grp  = lane >> 4;     // frag k-group
    const int rowBase = blockIdx.x * 64;

    float4v acc[4] = {};            // 4 n-tiles of 16x16, 4 f32 each

    for (int c = 0; c < 14; ++c) {
        // ---- stage A chunk: 64 rows x 64 k, f32 -> bf16 hi/lo
        #pragma unroll
        for (int rep = 0; rep < 4; ++rep) {
            const int idx  = rep * 256 + tid;   // 0..1023
            const int rLoc = idx >> 4;          // 0..63
            const int kq   = idx & 15;          // float4 slot
            const int r    = rowBase + rLoc;
            float4 v = make_float4(0.f, 0.f, 0.f, 0.f);
            if (r < NI) {
                if (c < 12)
                    v = *(const float4*)&F0[(size_t)r * DD0 + c * 64 + kq * 4];
                else
                    v = *(const float4*)&F1[(size_t)r * DD1 + (c - 12) * 64 + kq * 4];
            }
            const bf16pair p0 = f32_split_bf16(v.x);
            const bf16pair p1 = f32_split_bf16(v.y);
            const bf16pair p2 = f32_split_bf16(v.z);
            const bf16pair p3 = f32_split_bf16(v.w);
            short4v h4, l4;
            h4[0] = p0.hi; h4[1] = p1.hi; h4[2] = p2.hi; h4[3] = p3.hi;
            l4[0] = p0.lo; l4[1] = p1.lo; l4[2] = p2.lo; l4[3] = p3.lo;
            *(short4v*)&Ah[rLoc][kq * 4] = h4;
            *(short4v*)&Al[rLoc][kq * 4] = l4;
        }
        // ---- stage B chunk: 64 cols x 64 k (pre-converted, transposed)
        #pragma unroll
        for (int rep = 0; rep < 2; ++rep) {
            const int idx = rep * 256 + tid;    // 0..511
            const int col = idx >> 3;
            const int kq8 = idx & 7;
            *(short8v*)&Bh[col][kq8 * 8] =
                *(const short8v*)&WTh[(size_t)col * DD + c * 64 + kq8 * 8];
            *(short8v*)&Bl[col][kq8 * 8] =
                *(const short8v*)&WTl[(size_t)col * DD + c * 64 + kq8 * 8];
        }
        __syncthreads();

        // ---- MFMA: 2 k-steps x 4 n-tiles x 3 hi/lo combos
        #pragma unroll
        for (int ks = 0; ks < 2; ++ks) {
            const int ko = ks * 32 + grp * 8;
            const short8v ah = *(const short8v*)&Ah[wv * 16 + lr][ko];
            const short8v al = *(const short8v*)&Al[wv * 16 + lr][ko];
            #pragma unroll
            for (int nt = 0; nt < 4; ++nt) {
                const short8v bh = *(const short8v*)&Bh[nt * 16 + lr][ko];
                const short8v bl = *(const short8v*)&Bl[nt * 16 + lr][ko];
                acc[nt] = __builtin_amdgcn_mfma_f32_16x16x32_bf16(ah, bh, acc[nt], 0, 0, 0);
                acc[nt] = __builtin_amdgcn_mfma_f32_16x16x32_bf16(ah, bl, acc[nt], 0, 0, 0);
                acc[nt] = __builtin_amdgcn_mfma_f32_16x16x32_bf16(al, bh, acc[nt], 0, 0, 0);
            }
        }
        __syncthreads();
    }

    // ---- epilogue: bias, row L2-norm, write f32 acc + bf16 curS
    // C layout (m89): lane holds D[row = 4*grp + i][col = nt*16 + lr]
    float bias[4];
    #pragma unroll
    for (int nt = 0; nt < 4; ++nt) bias[nt] = b[nt * 16 + lr];

    float y[4][4];
    float ssp[4];                   // per-lane partial sum-of-squares per row i
    #pragma unroll
    for (int i = 0; i < 4; ++i) {
        ssp[i] = 0.f;
        #pragma unroll
        for (int nt = 0; nt < 4; ++nt) {
            y[nt][i] = acc[nt][i] + bias[nt];
            ssp[i] += y[nt][i] * y[nt][i];
        }
    }
    #pragma unroll
    for (int i = 0; i < 4; ++i) {
        float ss = ssp[i];
        ss += __shfl_xor(ss, 1);
        ss += __shfl_xor(ss, 2);
        ss += __shfl_xor(ss, 4);
        ss += __shfl_xor(ss, 8);
        const int r = rowBase + wv * 16 + 4 * grp + i;
        if (r < NI) {
            const float inv = 1.0f / fmaxf(sqrtf(ss), 1e-12f);
            const float dv  = dinv[NU + r];
            #pragma unroll
            for (int nt = 0; nt < 4; ++nt) {
                const float o = y[nt][i] * inv;
                acc_out[(size_t)(NU + r) * KDIM + nt * 16 + lr] = o;
                curS[(size_t)(NU + r) * KDIM + nt * 16 + lr] = f32_to_bf16_rne(o * dv);
            }
        }
    }
}

// user rows: acc = Gu (f32), curS = bf16(Gu * dinv[row])
__global__ void userinit_kernel(const float* __restrict__ Gu,
                                const float* __restrict__ dinv,
                                float* __restrict__ acc,
                                ushort_t* __restrict__ curS)
{
    const int i = blockIdx.x * blockDim.x + threadIdx.x;  // float4 index
    if (i < NU * KDIM / 4) {
        const int row = i >> 4;
        const float dv = dinv[row];
        const float4 g = ((const float4*)Gu)[i];
        ((float4*)acc)[i] = g;
        short4v s;
        s[0] = (short)f32_to_bf16_rne(g.x * dv);
        s[1] = (short)f32_to_bf16_rne(g.y * dv);
        s[2] = (short)f32_to_bf16_rne(g.z * dv);
        s[3] = (short)f32_to_bf16_rne(g.w * dv);
        *(short4v*)&curS[(size_t)i * 4] = s;
    }
}

// ---------------------------------------------------------------------------
// Partition: bucket 2M directed entries by dst>>7 (R7-proven).
// ---------------------------------------------------------------------------
__global__ __launch_bounds__(256) void part_kernel(
    const int* __restrict__ src, const int* __restrict__ dst,
    int* __restrict__ bcur, unsigned int* __restrict__ ents, int E2)
{
    __shared__ int bcntL[NB];
    __shared__ int bposL[NB];
    const int tid = threadIdx.x;
    const int pairBase = blockIdx.x * CHUNK_PAIRS;

    for (int i = tid; i < NB; i += 256) bcntL[i] = 0;
    __syncthreads();

    #pragma unroll
    for (int it = 0; it < CHUNK_PAIRS / 256; ++it) {
        const int p = pairBase + it * 256 + tid;
        if (p < E2) {
            const int u  = src[p];
            const int iF = dst[p];
            atomicAdd(&bcntL[iF >> 7], 1);
            atomicAdd(&bcntL[u  >> 7], 1);
        }
    }
    __syncthreads();

    for (int bkt = tid; bkt < NB; bkt += 256) {
        const int c = bcntL[bkt];
        bposL[bkt] = (c > 0) ? atomicAdd(&bcur[bkt], c) : 0;
        bcntL[bkt] = 0;
    }
    __syncthreads();

    #pragma unroll
    for (int it = 0; it < CHUNK_PAIRS / 256; ++it) {
        const int p = pairBase + it * 256 + tid;
        if (p < E2) {
            const int u  = src[p];
            const int iF = dst[p];
            {
                const int bkt = iF >> 7;
                const int k = bposL[bkt] + atomicAdd(&bcntL[bkt], 1);
                if (k < CAPB)
                    ents[(size_t)bkt * ENTS_STRIDE + k] =
                        ((unsigned int)(iF & 127) << 16) | (unsigned int)u;
            }
            {
                const int bkt = u >> 7;
                const int k = bposL[bkt] + atomicAdd(&bcntL[bkt], 1);
                if (k < CAPB)
                    ents[(size_t)bkt * ENTS_STRIDE + k] =
                        ((unsigned int)(u & 127) << 16) | (unsigned int)(iF - NU);
            }
        }
    }
}

// ---------------------------------------------------------------------------
// toELL: stage bucket entries in LDS, place into u16 ELL [row][CAP]; emits
// cnt + dinv. (ELL aliases the entry region; LDS staging makes that safe.)
// ---------------------------------------------------------------------------
__global__ __launch_bounds__(256) void toELL_kernel(
    const int* __restrict__ bcur, unsigned int* __restrict__ ents,
    ushort_t* __restrict__ col,
    int* __restrict__ cnt, float* __restrict__ dinv)
{
    __shared__ unsigned int eL[CAPB];
    __shared__ int curL[BROWS];
    const int bkt = blockIdx.x;
    const int tid = threadIdx.x;

    int n = bcur[bkt]; n = (n < CAPB) ? n : CAPB;
    const unsigned int* ep = ents + (size_t)bkt * ENTS_STRIDE;

    for (int j = tid; j < n; j += 256) eL[j] = ep[j];
    if (tid < BROWS) curL[tid] = 0;
    __syncthreads();

    const size_t rowB = (size_t)bkt * BROWS;
    for (int j = tid; j < n; j += 256) {
        const unsigned int e = eL[j];
        const int dl = (int)(e >> 16);
        const int slot = atomicAdd(&curL[dl], 1);
        if (slot < CAP)
            col[(rowB + dl) * CAP + slot] = (ushort_t)(e & 0xFFFFu);
    }
    __syncthreads();

    if (tid < BROWS) {
        int c = curL[tid];
        c = (c < CAP) ? c : CAP;
        const size_t row = rowB + tid;
        cnt[row]  = c;
        dinv[row] = (c > 0) ? rsqrtf((float)c) : 0.0f;
    }
}

// ---------------------------------------------------------------------------
// 3) pull over bf16 pre-scaled state: a = sum_j curS[col_j] (f32 accum)
//    acc[row] += dinv*a;  nxtS[row] = bf16(dinv^2*a)  (skipped last layer)
// ---------------------------------------------------------------------------
template <bool WRITE_NEXT>
__global__ __launch_bounds__(256) void pull_kernel(
    const ushort_t* __restrict__ curS, ushort_t* __restrict__ nxtS,
    float* __restrict__ acc,
    const int* __restrict__ cnt,
    const ushort_t* __restrict__ col,
    const float* __restrict__ dinv)
{
    const int row  = (blockIdx.x * blockDim.x + threadIdx.x) >> 6;
    const int lane = threadIdx.x & 63;
    if (row >= NN) return;

    const ushort_t* cp = col + (size_t)row * CAP;
    const int addB = (row < NU) ? NU : 0;
    const int n = cnt[row];

    float a0 = 0.0f, a1 = 0.0f;
    int j = 0;
    for (; j + 8 <= n; j += 8) {
        int s[8];
        #pragma unroll
        for (int q = 0; q < 8; ++q) s[q] = (int)cp[j + q] + addB;
        float v[8];
        #pragma unroll
        for (int q = 0; q < 8; ++q)
            v[q] = bf16bits_to_f32(curS[(size_t)s[q] * KDIM + lane]);
        a0 += v[0] + v[2] + v[4] + v[6];
        a1 += v[1] + v[3] + v[5] + v[7];
    }
    for (; j < n; ++j)
        a0 += bf16bits_to_f32(curS[(size_t)((int)cp[j] + addB) * KDIM + lane]);

    const float a  = a0 + a1;
    const float dv = dinv[row];
    const float val = dv * a;
    acc[(size_t)row * KDIM + lane] += val;
    if (WRITE_NEXT)
        nxtS[(size_t)row * KDIM + lane] = f32_to_bf16_rne(dv * val);
}

// ---------------------------------------------------------------------------
// 4) xui[b] = (1/16) * dot(acc[user[b]], acc[NU + item[b]])
// ---------------------------------------------------------------------------
__global__ __launch_bounds__(256) void out_kernel(
    const float* __restrict__ acc, const int* __restrict__ uidx,
    const int* __restrict__ iidx, float* __restrict__ out, int B)
{
    const int wid  = (blockIdx.x * blockDim.x + threadIdx.x) >> 6;
    const int lane = threadIdx.x & 63;
    if (wid >= B) return;
    const int u  = uidx[wid];
    const int it = iidx[wid];
    float p = acc[(size_t)u * KDIM + lane] * acc[(size_t)(NU + it) * KDIM + lane];
    #pragma unroll
    for (int m = 32; m >= 1; m >>= 1) p += __shfl_xor(p, m);
    if (lane == 0) out[wid] = p * (1.0f / 16.0f);
}

extern "C" void kernel_launch(void* const* d_in, const int* in_sizes, int n_in,
                              void* d_out, int out_size, void* d_ws, size_t ws_size,
                              hipStream_t stream)
{
    const float* Gu = (const float*)d_in[0];
    const float* F0 = (const float*)d_in[1];
    const float* F1 = (const float*)d_in[2];
    const float* W  = (const float*)d_in[3];
    const float* pb = (const float*)d_in[4];
    const int* edge = (const int*)d_in[5];
    const int* uidx = (const int*)d_in[6];
    const int* iidx = (const int*)d_in[7];
    const int E  = in_sizes[5] / 2;      // 2,000,000 directed edges
    const int E2 = E / 2;                // 1,000,000 mirrored pairs
    const int B = in_sizes[6];           // 4096
    const int* srcp = edge;              // first E2: user ids
    const int* dstp = edge + E;          // first E2: item ids (+NU)

    const size_t XE = (size_t)NN * KDIM;
    float*    acc   = (float*)d_ws;                        // XE f32
    ushort_t* curA  = (ushort_t*)(acc + XE);               // XE bf16
    ushort_t* curB  = curA + XE;                           // XE bf16
    float*    dinv  = (float*)(curB + XE);                 // NN
    int*      cnt   = (int*)(dinv + NN);                   // NN
    int*      bcur  = cnt + NN;                            // NB
    short*    WTh   = (short*)(bcur + NB);                 // 64*896
    short*    WTl   = WTh + (size_t)KDIM * DD;             // 64*896
    ushort_t* col   = (ushort_t*)(WTl + (size_t)KDIM * DD);
    unsigned int* ents = (unsigned int*)col;               // aliased region

    // build: partition -> bucket-local ELL (emits cnt, dinv)
    (void)hipMemsetAsync(bcur, 0, NB * sizeof(int), stream);
    part_kernel<<<(E2 + CHUNK_PAIRS - 1) / CHUNK_PAIRS, 256, 0, stream>>>(
        srcp, dstp, bcur, ents, E2);
    toELL_kernel<<<NB, 256, 0, stream>>>(bcur, ents, col, cnt, dinv);

    // W -> transposed bf16 hi/lo
    wtcvt_kernel<<<(DD * KDIM + 255) / 256, 256, 0, stream>>>(W, WTh, WTl);

    // x0: acc = [Gu; Fproj] f32, curA = bf16(dinv .* x0)
    userinit_kernel<<<(NU * KDIM / 4 + 255) / 256, 256, 0, stream>>>(
        Gu, dinv, acc, curA);
    proj_kernel<<<(NI + 63) / 64, 256, 0, stream>>>(F0, F1, WTh, WTl, pb,
                                                    dinv, acc, curA);

    // 3 propagation layers
    const int pullGrid = (int)((XE + 255) / 256);
    pull_kernel<true ><<<pullGrid, 256, 0, stream>>>(curA, curB, acc, cnt, col, dinv);
    pull_kernel<true ><<<pullGrid, 256, 0, stream>>>(curB, curA, acc, cnt, col, dinv);
    pull_kernel<false><<<pullGrid, 256, 0, stream>>>(curA, nullptr, acc, cnt, col, dinv);

    out_kernel<<<(int)(((size_t)B * 64 + 255) / 256), 256, 0, stream>>>(
        acc, uidx, iidx, (float*)d_out, B);
}

// Round 10
// 274.929 us; speedup vs baseline: 9.3169x; 1.0383x over previous
//
#include <hip/hip_runtime.h>
#include <hip/hip_bf16.h>

#define NU 50000
#define NI 30000
#define NN 80000     // NU + NI
#define KDIM 64
#define DD0 768
#define DD1 128
#define DD 896       // DD0 + DD1 = 14 chunks of 64

#define BROWS 128            // dst rows per bucket
#define NB (NN / BROWS)      // 625 buckets
#define CAPB 5120            // entries per bucket region
#define CAP 96               // uniform ELL capacity per row (u16 slots)
#define REGION_BYTES 24576   // per-bucket region
#define ENTS_STRIDE (REGION_BYTES / 4)
#define CHUNK_PAIRS 4096

typedef __attribute__((ext_vector_type(8))) short short8v;
typedef __attribute__((ext_vector_type(4))) short short4v;
typedef __attribute__((ext_vector_type(4))) float float4v;
typedef unsigned short ushort_t;

struct bf16pair { short hi, lo; };

__device__ inline bf16pair f32_split_bf16(float v) {
    __hip_bfloat16 h = __float2bfloat16(v);
    float hf = __bfloat162float(h);
    __hip_bfloat16 l = __float2bfloat16(v - hf);
    bf16pair p;
    p.hi = *reinterpret_cast<short*>(&h);
    p.lo = *reinterpret_cast<short*>(&l);
    return p;
}

__device__ inline float bf16bits_to_f32(ushort_t u) {
    return __uint_as_float(((unsigned int)u) << 16);
}

__device__ inline ushort_t f32_to_bf16_rne(float f) {
    unsigned int u = __float_as_uint(f);
    unsigned int r = (u + 0x7FFFu + ((u >> 16) & 1u)) >> 16;
    return (ushort_t)r;
}

// ---------------------------------------------------------------------------
// W -> transposed bf16 hi/lo:  WTh/WTl[col][k]
// ---------------------------------------------------------------------------
__global__ void wtcvt_kernel(const float* __restrict__ W,
                             short* __restrict__ WTh, short* __restrict__ WTl)
{
    const int i = blockIdx.x * 256 + threadIdx.x;   // over DD*KDIM
    if (i < DD * KDIM) {
        const int k = i >> 6, col = i & 63;
        const bf16pair p = f32_split_bf16(W[i]);
        WTh[col * DD + k] = p.hi;
        WTl[col * DD + k] = p.lo;
    }
}

// ---------------------------------------------------------------------------
// 1) proj via bf16x2-split MFMA with register-prefetch pipeline (T14):
// per chunk: {regs->LDS (convert); issue loads(c+1); barrier; MFMA(c); barrier}
// so next-chunk HBM latency hides under the MFMA phase + barriers.
// ---------------------------------------------------------------------------
__global__ __launch_bounds__(256) void proj_kernel(
    const float* __restrict__ F0, const float* __restrict__ F1,
    const short* __restrict__ WTh, const short* __restrict__ WTl,
    const float* __restrict__ b, const float* __restrict__ dinv,
    float* __restrict__ acc_out, ushort_t* __restrict__ curS)
{
    __shared__ short Ah[64][72];
    __shared__ short Al[64][72];
    __shared__ short Bh[64][72];
    __shared__ short Bl[64][72];

    const int tid  = threadIdx.x;
    const int wv   = tid >> 6;      // wave 0..3
    const int lane = tid & 63;
    const int lr   = lane & 15;     // frag row/col
    const int grp  = lane >> 4;     // frag k-group
    const int rowBase = blockIdx.x * 64;

    // per-thread staging indices (constant across chunks)
    const int aR[4] = { (0*256+tid) >> 4, (1*256+tid) >> 4,
                        (2*256+tid) >> 4, (3*256+tid) >> 4 };
    const int aK    = (tid & 15) * 4;           // same for all reps
    const int bCol[2] = { (0*256+tid) >> 3, (1*256+tid) >> 3 };
    const int bK      = (tid & 7) * 8;

    float4   pA[4];
    short8v  pBh[2], pBl[2];

    auto loadChunk = [&](int c) {
        #pragma unroll
        for (int rep = 0; rep < 4; ++rep) {
            const int r = rowBase + aR[rep];
            float4 v = make_float4(0.f, 0.f, 0.f, 0.f);
            if (r < NI) {
                if (c < 12)
                    v = *(const float4*)&F0[(size_t)r * DD0 + c * 64 + aK];
                else
                    v = *(const float4*)&F1[(size_t)r * DD1 + (c - 12) * 64 + aK];
            }
            pA[rep] = v;
        }
        #pragma unroll
        for (int rep = 0; rep < 2; ++rep) {
            pBh[rep] = *(const short8v*)&WTh[(size_t)bCol[rep] * DD + c * 64 + bK];
            pBl[rep] = *(const short8v*)&WTl[(size_t)bCol[rep] * DD + c * 64 + bK];
        }
    };

    float4v acc[4] = {};            // 4 n-tiles of 16x16, 4 f32 each

    loadChunk(0);
    for (int c = 0; c < 14; ++c) {
        // ---- regs -> LDS (A converted to bf16 hi/lo)
        #pragma unroll
        for (int rep = 0; rep < 4; ++rep) {
            const float4 v = pA[rep];
            const bf16pair p0 = f32_split_bf16(v.x);
            const bf16pair p1 = f32_split_bf16(v.y);
            const bf16pair p2 = f32_split_bf16(v.z);
            const bf16pair p3 = f32_split_bf16(v.w);
            short4v h4, l4;
            h4[0] = p0.hi; h4[1] = p1.hi; h4[2] = p2.hi; h4[3] = p3.hi;
            l4[0] = p0.lo; l4[1] = p1.lo; l4[2] = p2.lo; l4[3] = p3.lo;
            *(short4v*)&Ah[aR[rep]][aK] = h4;
            *(short4v*)&Al[aR[rep]][aK] = l4;
        }
        #pragma unroll
        for (int rep = 0; rep < 2; ++rep) {
            *(short8v*)&Bh[bCol[rep]][bK] = pBh[rep];
            *(short8v*)&Bl[bCol[rep]][bK] = pBl[rep];
        }
        if (c < 13) loadChunk(c + 1);   // async: in flight across MFMA phase
        __syncthreads();

        // ---- MFMA: 2 k-steps x 4 n-tiles x 3 hi/lo combos
        #pragma unroll
        for (int ks = 0; ks < 2; ++ks) {
            const int ko = ks * 32 + grp * 8;
            const short8v ah = *(const short8v*)&Ah[wv * 16 + lr][ko];
            const short8v al = *(const short8v*)&Al[wv * 16 + lr][ko];
            #pragma unroll
            for (int nt = 0; nt < 4; ++nt) {
                const short8v bh = *(const short8v*)&Bh[nt * 16 + lr][ko];
                const short8v bl = *(const short8v*)&Bl[nt * 16 + lr][ko];
                acc[nt] = __builtin_amdgcn_mfma_f32_16x16x32_bf16(ah, bh, acc[nt], 0, 0, 0);
                acc[nt] = __builtin_amdgcn_mfma_f32_16x16x32_bf16(ah, bl, acc[nt], 0, 0, 0);
                acc[nt] = __builtin_amdgcn_mfma_f32_16x16x32_bf16(al, bh, acc[nt], 0, 0, 0);
            }
        }
        __syncthreads();
    }

    // ---- epilogue: bias, row L2-norm, write f32 acc + bf16 curS
    float bias[4];
    #pragma unroll
    for (int nt = 0; nt < 4; ++nt) bias[nt] = b[nt * 16 + lr];

    float y[4][4];
    float ssp[4];
    #pragma unroll
    for (int i = 0; i < 4; ++i) {
        ssp[i] = 0.f;
        #pragma unroll
        for (int nt = 0; nt < 4; ++nt) {
            y[nt][i] = acc[nt][i] + bias[nt];
            ssp[i] += y[nt][i] * y[nt][i];
        }
    }
    #pragma unroll
    for (int i = 0; i < 4; ++i) {
        float ss = ssp[i];
        ss += __shfl_xor(ss, 1);
        ss += __shfl_xor(ss, 2);
        ss += __shfl_xor(ss, 4);
        ss += __shfl_xor(ss, 8);
        const int r = rowBase + wv * 16 + 4 * grp + i;
        if (r < NI) {
            const float inv = 1.0f / fmaxf(sqrtf(ss), 1e-12f);
            const float dv  = dinv[NU + r];
            #pragma unroll
            for (int nt = 0; nt < 4; ++nt) {
                const float o = y[nt][i] * inv;
                acc_out[(size_t)(NU + r) * KDIM + nt * 16 + lr] = o;
                curS[(size_t)(NU + r) * KDIM + nt * 16 + lr] = f32_to_bf16_rne(o * dv);
            }
        }
    }
}

// user rows: acc = Gu (f32), curS = bf16(Gu * dinv[row])
__global__ void userinit_kernel(const float* __restrict__ Gu,
                                const float* __restrict__ dinv,
                                float* __restrict__ acc,
                                ushort_t* __restrict__ curS)
{
    const int i = blockIdx.x * blockDim.x + threadIdx.x;  // float4 index
    if (i < NU * KDIM / 4) {
        const int row = i >> 4;
        const float dv = dinv[row];
        const float4 g = ((const float4*)Gu)[i];
        ((float4*)acc)[i] = g;
        short4v s;
        s[0] = (short)f32_to_bf16_rne(g.x * dv);
        s[1] = (short)f32_to_bf16_rne(g.y * dv);
        s[2] = (short)f32_to_bf16_rne(g.z * dv);
        s[3] = (short)f32_to_bf16_rne(g.w * dv);
        *(short4v*)&curS[(size_t)i * 4] = s;
    }
}

// ---------------------------------------------------------------------------
// Partition: bucket 2M directed entries by dst>>7 (R7-proven).
// ---------------------------------------------------------------------------
__global__ __launch_bounds__(256) void part_kernel(
    const int* __restrict__ src, const int* __restrict__ dst,
    int* __restrict__ bcur, unsigned int* __restrict__ ents, int E2)
{
    __shared__ int bcntL[NB];
    __shared__ int bposL[NB];
    const int tid = threadIdx.x;
    const int pairBase = blockIdx.x * CHUNK_PAIRS;

    for (int i = tid; i < NB; i += 256) bcntL[i] = 0;
    __syncthreads();

    #pragma unroll
    for (int it = 0; it < CHUNK_PAIRS / 256; ++it) {
        const int p = pairBase + it * 256 + tid;
        if (p < E2) {
            const int u  = src[p];
            const int iF = dst[p];
            atomicAdd(&bcntL[iF >> 7], 1);
            atomicAdd(&bcntL[u  >> 7], 1);
        }
    }
    __syncthreads();

    for (int bkt = tid; bkt < NB; bkt += 256) {
        const int c = bcntL[bkt];
        bposL[bkt] = (c > 0) ? atomicAdd(&bcur[bkt], c) : 0;
        bcntL[bkt] = 0;
    }
    __syncthreads();

    #pragma unroll
    for (int it = 0; it < CHUNK_PAIRS / 256; ++it) {
        const int p = pairBase + it * 256 + tid;
        if (p < E2) {
            const int u  = src[p];
            const int iF = dst[p];
            {
                const int bkt = iF >> 7;
                const int k = bposL[bkt] + atomicAdd(&bcntL[bkt], 1);
                if (k < CAPB)
                    ents[(size_t)bkt * ENTS_STRIDE + k] =
                        ((unsigned int)(iF & 127) << 16) | (unsigned int)u;
            }
            {
                const int bkt = u >> 7;
                const int k = bposL[bkt] + atomicAdd(&bcntL[bkt], 1);
                if (k < CAPB)
                    ents[(size_t)bkt * ENTS_STRIDE + k] =
                        ((unsigned int)(u & 127) << 16) | (unsigned int)(iF - NU);
            }
        }
    }
}

// ---------------------------------------------------------------------------
// toELL: stage bucket entries in LDS, place into u16 ELL [row][CAP]; emits
// cnt + dinv. (ELL aliases the entry region; LDS staging makes that safe.)
// ---------------------------------------------------------------------------
__global__ __launch_bounds__(256) void toELL_kernel(
    const int* __restrict__ bcur, unsigned int* __restrict__ ents,
    ushort_t* __restrict__ col,
    int* __restrict__ cnt, float* __restrict__ dinv)
{
    __shared__ unsigned int eL[CAPB];
    __shared__ int curL[BROWS];
    const int bkt = blockIdx.x;
    const int tid = threadIdx.x;

    int n = bcur[bkt]; n = (n < CAPB) ? n : CAPB;
    const unsigned int* ep = ents + (size_t)bkt * ENTS_STRIDE;

    for (int j = tid; j < n; j += 256) eL[j] = ep[j];
    if (tid < BROWS) curL[tid] = 0;
    __syncthreads();

    const size_t rowB = (size_t)bkt * BROWS;
    for (int j = tid; j < n; j += 256) {
        const unsigned int e = eL[j];
        const int dl = (int)(e >> 16);
        const int slot = atomicAdd(&curL[dl], 1);
        if (slot < CAP)
            col[(rowB + dl) * CAP + slot] = (ushort_t)(e & 0xFFFFu);
    }
    __syncthreads();

    if (tid < BROWS) {
        int c = curL[tid];
        c = (c < CAP) ? c : CAP;
        const size_t row = rowB + tid;
        cnt[row]  = c;
        dinv[row] = (c > 0) ? rsqrtf((float)c) : 0.0f;
    }
}

// ---------------------------------------------------------------------------
// 3) pull over bf16 pre-scaled state, phase-split by dst side so each phase's
// gather working set is small (items: 3.84 MB -> L2-resident; users: 6.4 MB).
//    a = sum_j curS[col_j];  acc[row] += dinv*a;  nxtS[row] = bf16(dinv^2*a)
// ---------------------------------------------------------------------------
template <bool WRITE_NEXT>
__global__ __launch_bounds__(256) void pull_kernel(
    const ushort_t* __restrict__ curS, ushort_t* __restrict__ nxtS,
    float* __restrict__ acc,
    const int* __restrict__ cnt,
    const ushort_t* __restrict__ col,
    const float* __restrict__ dinv,
    int rowStart, int nRows)
{
    const int wid  = (blockIdx.x * blockDim.x + threadIdx.x) >> 6;
    const int lane = threadIdx.x & 63;
    if (wid >= nRows) return;
    const int row = rowStart + wid;

    const ushort_t* cp = col + (size_t)row * CAP;
    const int addB = (row < NU) ? NU : 0;
    const int n = cnt[row];

    float a0 = 0.0f, a1 = 0.0f;
    int j = 0;
    for (; j + 8 <= n; j += 8) {
        int s[8];
        #pragma unroll
        for (int q = 0; q < 8; ++q) s[q] = (int)cp[j + q] + addB;
        float v[8];
        #pragma unroll
        for (int q = 0; q < 8; ++q)
            v[q] = bf16bits_to_f32(curS[(size_t)s[q] * KDIM + lane]);
        a0 += v[0] + v[2] + v[4] + v[6];
        a1 += v[1] + v[3] + v[5] + v[7];
    }
    for (; j < n; ++j)
        a0 += bf16bits_to_f32(curS[(size_t)((int)cp[j] + addB) * KDIM + lane]);

    const float a  = a0 + a1;
    const float dv = dinv[row];
    const float val = dv * a;
    acc[(size_t)row * KDIM + lane] += val;
    if (WRITE_NEXT)
        nxtS[(size_t)row * KDIM + lane] = f32_to_bf16_rne(dv * val);
}

// ---------------------------------------------------------------------------
// 4) xui[b] = (1/16) * dot(acc[user[b]], acc[NU + item[b]])
// ---------------------------------------------------------------------------
__global__ __launch_bounds__(256) void out_kernel(
    const float* __restrict__ acc, const int* __restrict__ uidx,
    const int* __restrict__ iidx, float* __restrict__ out, int B)
{
    const int wid  = (blockIdx.x * blockDim.x + threadIdx.x) >> 6;
    const int lane = threadIdx.x & 63;
    if (wid >= B) return;
    const int u  = uidx[wid];
    const int it = iidx[wid];
    float p = acc[(size_t)u * KDIM + lane] * acc[(size_t)(NU + it) * KDIM + lane];
    #pragma unroll
    for (int m = 32; m >= 1; m >>= 1) p += __shfl_xor(p, m);
    if (lane == 0) out[wid] = p * (1.0f / 16.0f);
}

extern "C" void kernel_launch(void* const* d_in, const int* in_sizes, int n_in,
                              void* d_out, int out_size, void* d_ws, size_t ws_size,
                              hipStream_t stream)
{
    const float* Gu = (const float*)d_in[0];
    const float* F0 = (const float*)d_in[1];
    const float* F1 = (const float*)d_in[2];
    const float* W  = (const float*)d_in[3];
    const float* pb = (const float*)d_in[4];
    const int* edge = (const int*)d_in[5];
    const int* uidx = (const int*)d_in[6];
    const int* iidx = (const int*)d_in[7];
    const int E  = in_sizes[5] / 2;      // 2,000,000 directed edges
    const int E2 = E / 2;                // 1,000,000 mirrored pairs
    const int B = in_sizes[6];           // 4096
    const int* srcp = edge;              // first E2: user ids
    const int* dstp = edge + E;          // first E2: item ids (+NU)

    const size_t XE = (size_t)NN * KDIM;
    float*    acc   = (float*)d_ws;                        // XE f32
    ushort_t* curA  = (ushort_t*)(acc + XE);               // XE bf16
    ushort_t* curB  = curA + XE;                           // XE bf16
    float*    dinv  = (float*)(curB + XE);                 // NN
    int*      cnt   = (int*)(dinv + NN);                   // NN
    int*      bcur  = cnt + NN;                            // NB
    short*    WTh   = (short*)(bcur + NB);                 // 64*896
    short*    WTl   = WTh + (size_t)KDIM * DD;             // 64*896
    ushort_t* col   = (ushort_t*)(WTl + (size_t)KDIM * DD);
    unsigned int* ents = (unsigned int*)col;               // aliased region

    // build: partition -> bucket-local ELL (emits cnt, dinv)
    (void)hipMemsetAsync(bcur, 0, NB * sizeof(int), stream);
    part_kernel<<<(E2 + CHUNK_PAIRS - 1) / CHUNK_PAIRS, 256, 0, stream>>>(
        srcp, dstp, bcur, ents, E2);
    toELL_kernel<<<NB, 256, 0, stream>>>(bcur, ents, col, cnt, dinv);

    // W -> transposed bf16 hi/lo
    wtcvt_kernel<<<(DD * KDIM + 255) / 256, 256, 0, stream>>>(W, WTh, WTl);

    // x0: acc = [Gu; Fproj] f32, curA = bf16(dinv .* x0)
    userinit_kernel<<<(NU * KDIM / 4 + 255) / 256, 256, 0, stream>>>(
        Gu, dinv, acc, curA);
    proj_kernel<<<(NI + 63) / 64, 256, 0, stream>>>(F0, F1, WTh, WTl, pb,
                                                    dinv, acc, curA);

    // 3 propagation layers, phase-split by dst side (L2 locality per phase)
    const int gridU = (NU * 64 + 255) / 256;
    const int gridI = (NI * 64 + 255) / 256;
    // layer 1: curA -> curB
    pull_kernel<true ><<<gridU, 256, 0, stream>>>(curA, curB, acc, cnt, col, dinv, 0, NU);
    pull_kernel<true ><<<gridI, 256, 0, stream>>>(curA, curB, acc, cnt, col, dinv, NU, NI);
    // layer 2: curB -> curA
    pull_kernel<true ><<<gridU, 256, 0, stream>>>(curB, curA, acc, cnt, col, dinv, 0, NU);
    pull_kernel<true ><<<gridI, 256, 0, stream>>>(curB, curA, acc, cnt, col, dinv, NU, NI);
    // layer 3: curA -> (acc only)
    pull_kernel<false><<<gridU, 256, 0, stream>>>(curA, nullptr, acc, cnt, col, dinv, 0, NU);
    pull_kernel<false><<<gridI, 256, 0, stream>>>(curA, nullptr, acc, cnt, col, dinv, NU, NI);

    out_kernel<<<(int)(((size_t)B * 64 + 255) / 256), 256, 0, stream>>>(
        acc, uidx, iidx, (float*)d_out, B);
}

// Round 11
// 231.096 us; speedup vs baseline: 11.0841x; 1.1897x over previous
//
#include <hip/hip_runtime.h>
#include <hip/hip_bf16.h>

#define NU 50000
#define NI 30000
#define NN 80000     // NU + NI
#define KDIM 64
#define DD0 768
#define DD1 128
#define DD 896       // DD0 + DD1 = 14 chunks of 64

#define BROWS 128            // dst rows per bucket
#define NB (NN / BROWS)      // 625 buckets
#define CAPB 5120            // entries per bucket region
#define CAP 96               // uniform ELL capacity per row (u16 slots)
#define REGION_BYTES 24576   // per-bucket region
#define ENTS_STRIDE (REGION_BYTES / 4)
#define CHUNK_PAIRS 4096

typedef __attribute__((ext_vector_type(8))) short short8v;
typedef __attribute__((ext_vector_type(4))) short short4v;
typedef __attribute__((ext_vector_type(4))) float float4v;
typedef unsigned short ushort_t;

struct bf16pair { short hi, lo; };

__device__ inline bf16pair f32_split_bf16(float v) {
    __hip_bfloat16 h = __float2bfloat16(v);
    float hf = __bfloat162float(h);
    __hip_bfloat16 l = __float2bfloat16(v - hf);
    bf16pair p;
    p.hi = *reinterpret_cast<short*>(&h);
    p.lo = *reinterpret_cast<short*>(&l);
    return p;
}

__device__ inline float bf16bits_to_f32(ushort_t u) {
    return __uint_as_float(((unsigned int)u) << 16);
}

__device__ inline ushort_t f32_to_bf16_rne(float f) {
    unsigned int u = __float_as_uint(f);
    unsigned int r = (u + 0x7FFFu + ((u >> 16) & 1u)) >> 16;
    return (ushort_t)r;
}

// ---------------------------------------------------------------------------
// W -> transposed bf16 hi/lo:  WTh/WTl[col][k]
// ---------------------------------------------------------------------------
__global__ void wtcvt_kernel(const float* __restrict__ W,
                             short* __restrict__ WTh, short* __restrict__ WTl)
{
    const int i = blockIdx.x * 256 + threadIdx.x;   // over DD*KDIM
    if (i < DD * KDIM) {
        const int k = i >> 6, col = i & 63;
        const bf16pair p = f32_split_bf16(W[i]);
        WTh[col * DD + k] = p.hi;
        WTl[col * DD + k] = p.lo;
    }
}

// ---------------------------------------------------------------------------
// 1) proj via bf16x2-split MFMA. 16-row tiles -> 1875 blocks (~6 blocks/CU,
// high occupancy). Block = 4 waves; wave w owns n-tile w (cols w*16..+15).
// Register-prefetch pipeline: {regs->LDS; issue loads(c+1); barrier; MFMA;
// barrier}. Row L2-norm needs a cross-wave LDS reduction (each wave holds
// only 16 of a row's 64 cols).
// Writes f32 item rows into Fp, bf16 dinv-scaled rows into curS.
// ---------------------------------------------------------------------------
__global__ __launch_bounds__(256) void proj_kernel(
    const float* __restrict__ F0, const float* __restrict__ F1,
    const short* __restrict__ WTh, const short* __restrict__ WTl,
    const float* __restrict__ b, const float* __restrict__ dinv,
    float* __restrict__ Fp, ushort_t* __restrict__ curS)
{
    __shared__ short Ah[16][72];
    __shared__ short Al[16][72];
    __shared__ short Bh[64][72];
    __shared__ short Bl[64][72];
    __shared__ float ssL[4][16];

    const int tid  = threadIdx.x;
    const int wv   = tid >> 6;      // wave 0..3 = n-tile index
    const int lane = tid & 63;
    const int lr   = lane & 15;
    const int grp  = lane >> 4;
    const int rowBase = blockIdx.x * 16;

    // staging indices
    const int aR = tid >> 4;            // 0..15
    const int aK = (tid & 15) * 4;
    const int bC0 = tid >> 3;           // 0..31
    const int bC1 = (256 + tid) >> 3;   // 32..63
    const int bK  = (tid & 7) * 8;

    float4  pA;
    short8v pBh0, pBh1, pBl0, pBl1;

    auto loadChunk = [&](int c) {
        const int r = rowBase + aR;
        float4 v = make_float4(0.f, 0.f, 0.f, 0.f);
        if (r < NI) {
            if (c < 12)
                v = *(const float4*)&F0[(size_t)r * DD0 + c * 64 + aK];
            else
                v = *(const float4*)&F1[(size_t)r * DD1 + (c - 12) * 64 + aK];
        }
        pA = v;
        pBh0 = *(const short8v*)&WTh[(size_t)bC0 * DD + c * 64 + bK];
        pBh1 = *(const short8v*)&WTh[(size_t)bC1 * DD + c * 64 + bK];
        pBl0 = *(const short8v*)&WTl[(size_t)bC0 * DD + c * 64 + bK];
        pBl1 = *(const short8v*)&WTl[(size_t)bC1 * DD + c * 64 + bK];
    };

    float4v acc = {};

    loadChunk(0);
    for (int c = 0; c < 14; ++c) {
        // regs -> LDS
        {
            const bf16pair p0 = f32_split_bf16(pA.x);
            const bf16pair p1 = f32_split_bf16(pA.y);
            const bf16pair p2 = f32_split_bf16(pA.z);
            const bf16pair p3 = f32_split_bf16(pA.w);
            short4v h4, l4;
            h4[0] = p0.hi; h4[1] = p1.hi; h4[2] = p2.hi; h4[3] = p3.hi;
            l4[0] = p0.lo; l4[1] = p1.lo; l4[2] = p2.lo; l4[3] = p3.lo;
            *(short4v*)&Ah[aR][aK] = h4;
            *(short4v*)&Al[aR][aK] = l4;
            *(short8v*)&Bh[bC0][bK] = pBh0;
            *(short8v*)&Bh[bC1][bK] = pBh1;
            *(short8v*)&Bl[bC0][bK] = pBl0;
            *(short8v*)&Bl[bC1][bK] = pBl1;
        }
        if (c < 13) loadChunk(c + 1);   // in flight across MFMA phase
        __syncthreads();

        #pragma unroll
        for (int ks = 0; ks < 2; ++ks) {
            const int ko = ks * 32 + grp * 8;
            const short8v ah = *(const short8v*)&Ah[lr][ko];
            const short8v al = *(const short8v*)&Al[lr][ko];
            const short8v bh = *(const short8v*)&Bh[wv * 16 + lr][ko];
            const short8v bl = *(const short8v*)&Bl[wv * 16 + lr][ko];
            acc = __builtin_amdgcn_mfma_f32_16x16x32_bf16(ah, bh, acc, 0, 0, 0);
            acc = __builtin_amdgcn_mfma_f32_16x16x32_bf16(ah, bl, acc, 0, 0, 0);
            acc = __builtin_amdgcn_mfma_f32_16x16x32_bf16(al, bh, acc, 0, 0, 0);
        }
        __syncthreads();
    }

    // epilogue: lane holds D[row=4*grp+i][col=wv*16+lr]
    const float bias = b[wv * 16 + lr];
    float y[4];
    float ssw[4];
    #pragma unroll
    for (int i = 0; i < 4; ++i) {
        y[i] = acc[i] + bias;
        float s = y[i] * y[i];
        s += __shfl_xor(s, 1);
        s += __shfl_xor(s, 2);
        s += __shfl_xor(s, 4);
        s += __shfl_xor(s, 8);
        ssw[i] = s;                     // per-wave partial (16 cols)
    }
    if (lr == 0) {
        #pragma unroll
        for (int i = 0; i < 4; ++i)
            ssL[wv][grp * 4 + i] = ssw[i];
    }
    __syncthreads();
    #pragma unroll
    for (int i = 0; i < 4; ++i) {
        const int rl = grp * 4 + i;
        const float ss = ssL[0][rl] + ssL[1][rl] + ssL[2][rl] + ssL[3][rl];
        const int r = rowBase + rl;
        if (r < NI) {
            const float inv = 1.0f / fmaxf(sqrtf(ss), 1e-12f);
            const float dv  = dinv[NU + r];
            const float o = y[i] * inv;
            Fp[(size_t)(NU + r) * KDIM + wv * 16 + lr] = o;
            curS[(size_t)(NU + r) * KDIM + wv * 16 + lr] = f32_to_bf16_rne(o * dv);
        }
    }
}

// user rows: curS = bf16(Gu * dinv[row])   (x0 for users is read from Gu)
__global__ void userinit_kernel(const float* __restrict__ Gu,
                                const float* __restrict__ dinv,
                                ushort_t* __restrict__ curS)
{
    const int i = blockIdx.x * blockDim.x + threadIdx.x;  // float4 index
    if (i < NU * KDIM / 4) {
        const int row = i >> 4;
        const float dv = dinv[row];
        const float4 g = ((const float4*)Gu)[i];
        short4v s;
        s[0] = (short)f32_to_bf16_rne(g.x * dv);
        s[1] = (short)f32_to_bf16_rne(g.y * dv);
        s[2] = (short)f32_to_bf16_rne(g.z * dv);
        s[3] = (short)f32_to_bf16_rne(g.w * dv);
        *(short4v*)&curS[(size_t)i * 4] = s;
    }
}

// ---------------------------------------------------------------------------
// Partition: bucket 2M directed entries by dst>>7 (R7-proven).
// ---------------------------------------------------------------------------
__global__ __launch_bounds__(256) void part_kernel(
    const int* __restrict__ src, const int* __restrict__ dst,
    int* __restrict__ bcur, unsigned int* __restrict__ ents, int E2)
{
    __shared__ int bcntL[NB];
    __shared__ int bposL[NB];
    const int tid = threadIdx.x;
    const int pairBase = blockIdx.x * CHUNK_PAIRS;

    for (int i = tid; i < NB; i += 256) bcntL[i] = 0;
    __syncthreads();

    #pragma unroll
    for (int it = 0; it < CHUNK_PAIRS / 256; ++it) {
        const int p = pairBase + it * 256 + tid;
        if (p < E2) {
            const int u  = src[p];
            const int iF = dst[p];
            atomicAdd(&bcntL[iF >> 7], 1);
            atomicAdd(&bcntL[u  >> 7], 1);
        }
    }
    __syncthreads();

    for (int bkt = tid; bkt < NB; bkt += 256) {
        const int c = bcntL[bkt];
        bposL[bkt] = (c > 0) ? atomicAdd(&bcur[bkt], c) : 0;
        bcntL[bkt] = 0;
    }
    __syncthreads();

    #pragma unroll
    for (int it = 0; it < CHUNK_PAIRS / 256; ++it) {
        const int p = pairBase + it * 256 + tid;
        if (p < E2) {
            const int u  = src[p];
            const int iF = dst[p];
            {
                const int bkt = iF >> 7;
                const int k = bposL[bkt] + atomicAdd(&bcntL[bkt], 1);
                if (k < CAPB)
                    ents[(size_t)bkt * ENTS_STRIDE + k] =
                        ((unsigned int)(iF & 127) << 16) | (unsigned int)u;
            }
            {
                const int bkt = u >> 7;
                const int k = bposL[bkt] + atomicAdd(&bcntL[bkt], 1);
                if (k < CAPB)
                    ents[(size_t)bkt * ENTS_STRIDE + k] =
                        ((unsigned int)(u & 127) << 16) | (unsigned int)(iF - NU);
            }
        }
    }
}

// ---------------------------------------------------------------------------
// toELL: stage bucket entries in LDS, place into u16 ELL [row][CAP]; emits
// cnt + dinv. (ELL aliases the entry region; LDS staging makes that safe.)
// ---------------------------------------------------------------------------
__global__ __launch_bounds__(256) void toELL_kernel(
    const int* __restrict__ bcur, unsigned int* __restrict__ ents,
    ushort_t* __restrict__ col,
    int* __restrict__ cnt, float* __restrict__ dinv)
{
    __shared__ unsigned int eL[CAPB];
    __shared__ int curL[BROWS];
    const int bkt = blockIdx.x;
    const int tid = threadIdx.x;

    int n = bcur[bkt]; n = (n < CAPB) ? n : CAPB;
    const unsigned int* ep = ents + (size_t)bkt * ENTS_STRIDE;

    for (int j = tid; j < n; j += 256) eL[j] = ep[j];
    if (tid < BROWS) curL[tid] = 0;
    __syncthreads();

    const size_t rowB = (size_t)bkt * BROWS;
    for (int j = tid; j < n; j += 256) {
        const unsigned int e = eL[j];
        const int dl = (int)(e >> 16);
        const int slot = atomicAdd(&curL[dl], 1);
        if (slot < CAP)
            col[(rowB + dl) * CAP + slot] = (ushort_t)(e & 0xFFFFu);
    }
    __syncthreads();

    if (tid < BROWS) {
        int c = curL[tid];
        c = (c < CAP) ? c : CAP;
        const size_t row = rowB + tid;
        cnt[row]  = c;
        dinv[row] = (c > 0) ? rsqrtf((float)c) : 0.0f;
    }
}

// ---------------------------------------------------------------------------
// 3) pull: nxtS[row] = bf16( dinv[row]^2 * sum_j curS[col_j] ).
// No acc RMW (the layer mean is reconstructed in out_kernel).
// Phase-split by dst side for gather L2 locality.
// ---------------------------------------------------------------------------
__global__ __launch_bounds__(256) void pull_kernel(
    const ushort_t* __restrict__ curS, ushort_t* __restrict__ nxtS,
    const int* __restrict__ cnt,
    const ushort_t* __restrict__ col,
    const float* __restrict__ dinv,
    int rowStart, int nRows)
{
    const int wid  = (blockIdx.x * blockDim.x + threadIdx.x) >> 6;
    const int lane = threadIdx.x & 63;
    if (wid >= nRows) return;
    const int row = rowStart + wid;

    const ushort_t* cp = col + (size_t)row * CAP;
    const int addB = (row < NU) ? NU : 0;
    const int n = cnt[row];

    float a0 = 0.0f, a1 = 0.0f;
    int j = 0;
    for (; j + 8 <= n; j += 8) {
        int s[8];
        #pragma unroll
        for (int q = 0; q < 8; ++q) s[q] = (int)cp[j + q] + addB;
        float v[8];
        #pragma unroll
        for (int q = 0; q < 8; ++q)
            v[q] = bf16bits_to_f32(curS[(size_t)s[q] * KDIM + lane]);
        a0 += v[0] + v[2] + v[4] + v[6];
        a1 += v[1] + v[3] + v[5] + v[7];
    }
    for (; j < n; ++j)
        a0 += bf16bits_to_f32(curS[(size_t)((int)cp[j] + addB) * KDIM + lane]);

    const float dv = dinv[row];
    nxtS[(size_t)row * KDIM + lane] = f32_to_bf16_rne(dv * dv * (a0 + a1));
}

// ---------------------------------------------------------------------------
// 4) out: acc_r = x0_r + (S1_r + S2_r)/dinv_r + dinv_r * sum_j S2[col_j(r)]
//    xui[b] = (1/16) * dot(acc_u, acc_i).  Layer-3 evaluated only here,
//    at the <=8192 sampled rows (262K gathers vs 2M for a full layer).
// ---------------------------------------------------------------------------
__device__ inline float row_acc(int row, float x0, int lane,
                                const ushort_t* __restrict__ S1,
                                const ushort_t* __restrict__ S2,
                                const int* __restrict__ cnt,
                                const ushort_t* __restrict__ col,
                                const float* __restrict__ dinv)
{
    const float dv  = dinv[row];
    const float rdv = (dv > 0.f) ? 1.0f / dv : 0.0f;
    const float s1 = bf16bits_to_f32(S1[(size_t)row * KDIM + lane]);
    const float s2 = bf16bits_to_f32(S2[(size_t)row * KDIM + lane]);

    const ushort_t* cp = col + (size_t)row * CAP;
    const int addB = (row < NU) ? NU : 0;
    const int n = cnt[row];
    float a0 = 0.0f, a1 = 0.0f;
    int j = 0;
    for (; j + 8 <= n; j += 8) {
        int s[8];
        #pragma unroll
        for (int q = 0; q < 8; ++q) s[q] = (int)cp[j + q] + addB;
        float v[8];
        #pragma unroll
        for (int q = 0; q < 8; ++q)
            v[q] = bf16bits_to_f32(S2[(size_t)s[q] * KDIM + lane]);
        a0 += v[0] + v[2] + v[4] + v[6];
        a1 += v[1] + v[3] + v[5] + v[7];
    }
    for (; j < n; ++j)
        a0 += bf16bits_to_f32(S2[(size_t)((int)cp[j] + addB) * KDIM + lane]);

    return x0 + (s1 + s2) * rdv + dv * (a0 + a1);
}

__global__ __launch_bounds__(256) void out_kernel(
    const float* __restrict__ Gu, const float* __restrict__ Fp,
    const ushort_t* __restrict__ S1, const ushort_t* __restrict__ S2,
    const int* __restrict__ cnt, const ushort_t* __restrict__ col,
    const float* __restrict__ dinv,
    const int* __restrict__ uidx, const int* __restrict__ iidx,
    float* __restrict__ out, int B)
{
    const int wid  = (blockIdx.x * blockDim.x + threadIdx.x) >> 6;
    const int lane = threadIdx.x & 63;
    if (wid >= B) return;
    const int u  = uidx[wid];
    const int rI = NU + iidx[wid];

    const float au = row_acc(u,  Gu[(size_t)u  * KDIM + lane], lane,
                             S1, S2, cnt, col, dinv);
    const float ai = row_acc(rI, Fp[(size_t)rI * KDIM + lane], lane,
                             S1, S2, cnt, col, dinv);
    float p = au * ai;
    #pragma unroll
    for (int m = 32; m >= 1; m >>= 1) p += __shfl_xor(p, m);
    if (lane == 0) out[wid] = p * (1.0f / 16.0f);
}

extern "C" void kernel_launch(void* const* d_in, const int* in_sizes, int n_in,
                              void* d_out, int out_size, void* d_ws, size_t ws_size,
                              hipStream_t stream)
{
    const float* Gu = (const float*)d_in[0];
    const float* F0 = (const float*)d_in[1];
    const float* F1 = (const float*)d_in[2];
    const float* W  = (const float*)d_in[3];
    const float* pb = (const float*)d_in[4];
    const int* edge = (const int*)d_in[5];
    const int* uidx = (const int*)d_in[6];
    const int* iidx = (const int*)d_in[7];
    const int E  = in_sizes[5] / 2;      // 2,000,000 directed edges
    const int E2 = E / 2;                // 1,000,000 mirrored pairs
    const int B = in_sizes[6];           // 4096
    const int* srcp = edge;              // first E2: user ids
    const int* dstp = edge + E;          // first E2: item ids (+NU)

    const size_t XE = (size_t)NN * KDIM;
    float*    Fp    = (float*)d_ws;                        // XE f32 (items)
    ushort_t* curA  = (ushort_t*)(Fp + XE);                // XE bf16
    ushort_t* curB  = curA + XE;                           // XE bf16
    float*    dinv  = (float*)(curB + XE);                 // NN
    int*      cnt   = (int*)(dinv + NN);                   // NN
    int*      bcur  = cnt + NN;                            // NB
    short*    WTh   = (short*)(bcur + NB);                 // 64*896
    short*    WTl   = WTh + (size_t)KDIM * DD;             // 64*896
    ushort_t* col   = (ushort_t*)(WTl + (size_t)KDIM * DD);
    unsigned int* ents = (unsigned int*)col;               // aliased region

    // build: partition -> bucket-local ELL (emits cnt, dinv)
    (void)hipMemsetAsync(bcur, 0, NB * sizeof(int), stream);
    part_kernel<<<(E2 + CHUNK_PAIRS - 1) / CHUNK_PAIRS, 256, 0, stream>>>(
        srcp, dstp, bcur, ents, E2);
    toELL_kernel<<<NB, 256, 0, stream>>>(bcur, ents, col, cnt, dinv);

    // W -> transposed bf16 hi/lo
    wtcvt_kernel<<<(DD * KDIM + 255) / 256, 256, 0, stream>>>(W, WTh, WTl);

    // S0: curA = bf16(dinv .* x0)  (x0 = [Gu; Fproj]; Fp keeps item x0 in f32)
    userinit_kernel<<<(NU * KDIM / 4 + 255) / 256, 256, 0, stream>>>(
        Gu, dinv, curA);
    proj_kernel<<<(NI + 15) / 16, 256, 0, stream>>>(F0, F1, WTh, WTl, pb,
                                                    dinv, Fp, curA);

    // layers 1-2 (phase-split); S1 = curB, S2 = curA (overwrites dead S0)
    const int gridU = (NU * 64 + 255) / 256;
    const int gridI = (NI * 64 + 255) / 256;
    pull_kernel<<<gridU, 256, 0, stream>>>(curA, curB, cnt, col, dinv, 0, NU);
    pull_kernel<<<gridI, 256, 0, stream>>>(curA, curB, cnt, col, dinv, NU, NI);
    pull_kernel<<<gridU, 256, 0, stream>>>(curB, curA, cnt, col, dinv, 0, NU);
    pull_kernel<<<gridI, 256, 0, stream>>>(curB, curA, cnt, col, dinv, NU, NI);

    // out: layer-3 at sampled rows only + mean + dot
    out_kernel<<<(int)(((size_t)B * 64 + 255) / 256), 256, 0, stream>>>(
        Gu, Fp, curB, curA, cnt, col, dinv, uidx, iidx, (float*)d_out, B);
}